// Round 12
// baseline (408.738 us; speedup 1.0000x reference)
//
#include <hip/hip_runtime.h>

// SemanticCaps dynamic routing, fp32. B=128, J=10, K=1152, M=16, I=8.
// R17: DIAGNOSTIC ROUND. Champion pipeline (R16 = R9 = 137.4-137.6 µs)
// byte-identical, plus 16 dead replicas of iter_kernel<1> appended (same
// inputs, write scratch sp2; out untouched). Purpose: measure the marginal
// cost of one MODE-1 routing pass + dispatch boundary as
//   X = (dur - 137.4) / 16.
// Three consecutive nulls (Ws LDS vs scalar [R6], pipelining [R11],
// barrier count 9->3 [R16]) mean the iter-internal theories are all dead
// or the passes are small and fixed costs dominate; X discriminates.
// Pre-committed: X>=18 -> iter passes dominate, attack u-compute core
// (bf16-MFMA / packed math). X<=14 -> boundaries/fill dominate, attack
// dispatch count or accept floor.
// b-logit algebra: b after t iters = u.(v0+..+v_{t-1}) (b starts at 0).
//
// ws (floats): sp[128*10*128*16] v0T[20480] vsumT[20480] sp2[128*10*128*16]

#define B_ 128
#define J_ 10
#define K_ 1152
#define M_ 16
#define I_ 8
#define KT 9
#define KB 3                 // k's per barrier interval
#define NIV (KT / KB)        // 3 intervals per pass
#define NKT (K_ / KT)        // 128 k-tiles
#define RW (K_ * I_)         // 9216 floats per x batch-row
#define SVEC (J_ * B_ * M_)  // 20480 floats per fold-slice of sp
#define XT4 (KT * I_ / 4)    // 18 float4 per b-row of the x tile

// ---------- routing pass -----------------------------------------------------
// MODE 0: c == 1 (iteration 0; 0.1 folded into squash<0>)
// MODE 1: c = softmax_j(u . vin);  s = sum_k c*u
template <int MODE>
__global__ __launch_bounds__(640)
void iter_kernel(const float* __restrict__ x, const float* __restrict__ Ws,
                 const float* __restrict__ vinT, float* __restrict__ sp) {
    __shared__ float xtile[KT * I_ * 64];       // 72 rows x 64 b = 18 KB
    __shared__ float earr[2][KB][J_ * 64];      // 15.4 KB, interval ping-pong
    const int t  = threadIdx.x;
    const int bl = t & 63;
    const int j  = __builtin_amdgcn_readfirstlane(t >> 6);  // wave-uniform j
    const int kt = blockIdx.x, bg = blockIdx.y;
    const int b  = bg * 64 + bl;

    // ---- stage + transpose x[bg*64..+64)[kt*72 .. +72) -> xtile[f][bb] -----
    {
        const float4* x4 = (const float4*)x;    // row stride RW/4 = 2304
        for (int idx = t; idx < 64 * XT4; idx += 640) {
            const int bb = idx / XT4, q = idx % XT4;
            const float4 w = x4[(size_t)(bg * 64 + bb) * (RW / 4) + kt * XT4 + q];
            xtile[(q * 4 + 0) * 64 + bb] = w.x;
            xtile[(q * 4 + 1) * 64 + bb] = w.y;
            xtile[(q * 4 + 2) * 64 + bb] = w.z;
            xtile[(q * 4 + 3) * 64 + bb] = w.w;
        }
    }

    float v[M_], s[M_];
#pragma unroll
    for (int m = 0; m < M_; ++m) s[m] = 0.f;
    if (MODE == 1) {
        const float4* vp = (const float4*)(vinT + ((size_t)j * B_ + b) * M_);
#pragma unroll
        for (int q = 0; q < 4; ++q) {
            const float4 w = vp[q];
            v[4*q] = w.x; v[4*q+1] = w.y; v[4*q+2] = w.z; v[4*q+3] = w.w;
        }
    }
    __syncthreads();   // x-tile ready

    const float* wb = Ws + ((size_t)j * K_ + (size_t)kt * KT) * (M_ * I_);

    for (int iv = 0; iv < NIV; ++iv) {
        const int par = iv & 1;
        float u[KB][M_];
#pragma unroll
        for (int kb = 0; kb < KB; ++kb) {
            const int kk = iv * KB + kb;
            float xr[I_];
#pragma unroll
            for (int i = 0; i < I_; ++i)
                xr[i] = xtile[(kk * I_ + i) * 64 + bl];
            const float* w = wb + (size_t)kk * (M_ * I_);   // uniform -> s_load
#pragma unroll
            for (int m = 0; m < M_; ++m) {
                float a = 0.f;
#pragma unroll
                for (int i = 0; i < I_; ++i) a += w[m * I_ + i] * xr[i];
                u[kb][m] = a;
            }
        }

        if (MODE == 1) {
            float e[KB];
#pragma unroll
            for (int kb = 0; kb < KB; ++kb) {
                float lg = 0.f;
#pragma unroll
                for (int m = 0; m < M_; ++m) lg += u[kb][m] * v[m];
                e[kb] = __expf(lg);
                earr[par][kb][j * 64 + bl] = e[kb];
            }
            __syncthreads();   // ONE barrier per 3 k's; parity makes reuse safe
#pragma unroll
            for (int kb = 0; kb < KB; ++kb) {
                float den = 0.f;
#pragma unroll
                for (int jj = 0; jj < J_; ++jj)
                    den += earr[par][kb][jj * 64 + bl];
                const float c = __fdividef(e[kb], den);
#pragma unroll
                for (int m = 0; m < M_; ++m) s[m] = fmaf(c, u[kb][m], s[m]);
            }
        } else {
#pragma unroll
            for (int kb = 0; kb < KB; ++kb)
#pragma unroll
                for (int m = 0; m < M_; ++m) s[m] += u[kb][m];
        }
    }

    float4* o = (float4*)(sp + (((size_t)kt * J_ + j) * B_ + b) * M_);
#pragma unroll
    for (int q = 0; q < 4; ++q) {
        float4 w;
        w.x = s[4*q]; w.y = s[4*q+1]; w.z = s[4*q+2]; w.w = s[4*q+3];
        o[q] = w;
    }
}

// ---------- squash: parallel fold of 128 tile-partials, emit v ---------------
// SM 0: v0T = squash(0.1*S)  SM 1: vsumT = v0T + squash(S)  SM 2: out = squash(S)
template <int SM>
__global__ __launch_bounds__(256)
void squash_kernel(const float* __restrict__ sp, const float* __restrict__ v0T,
                   float* __restrict__ dst) {
    __shared__ float red[4][64];
    const int t  = threadIdx.x;
    const int l  = t & 63;
    const int wv = t >> 6;
    const int g  = blockIdx.x * 64 + l;   // g = (j*128+b)*16+m
    const int m = g & 15;
    const int b = (g >> 4) & 127;
    const int j = g >> 11;
    const float* p = sp + (size_t)((j * B_ + b) * M_ + m);
    float S = 0.f;
#pragma unroll 8
    for (int tt = wv * (NKT / 4); tt < (wv + 1) * (NKT / 4); ++tt)
        S += p[(size_t)tt * SVEC];
    red[wv][l] = S;
    __syncthreads();
    if (wv == 0) {
        S = red[0][l] + red[1][l] + red[2][l] + red[3][l];
        if (SM == 0) S *= 0.1f;
        float sq = S * S;
        sq += __shfl_xor(sq, 1, 64);
        sq += __shfl_xor(sq, 2, 64);
        sq += __shfl_xor(sq, 4, 64);
        sq += __shfl_xor(sq, 8, 64);      // sum over m within 16-lane group
        const float n = sqrtf(sq);
        float v = S * (n / (1.f + sq));
        if (SM == 1) v += v0T[g];
        if (SM == 2) dst[((size_t)b * J_ + j) * M_ + m] = v;   // standard [b][j][m]
        else         dst[g] = v;                                // vT layout
    }
}

extern "C" void kernel_launch(void* const* d_in, const int* in_sizes, int n_in,
                              void* d_out, int out_size, void* d_ws, size_t ws_size,
                              hipStream_t stream) {
    const float* x  = (const float*)d_in[0];   // [128][1152][8]
    const float* Ws = (const float*)d_in[1];   // [10][1152][16][8]
    float* out = (float*)d_out;                // [128][10][16]

    float* sp    = (float*)d_ws;                           // 2,621,440 floats
    float* v0T   = sp + (size_t)NKT * SVEC;                //    20,480
    float* vsumT = v0T + SVEC;                             //    20,480
    float* sp2   = vsumT + SVEC;                           // 2,621,440 (scratch)

    // ---- the real pipeline (byte-identical to R16/R9 champion) ----
    iter_kernel<0><<<dim3(NKT, 2), 640, 0, stream>>>(x, Ws, nullptr, sp);
    squash_kernel<0><<<320, 256, 0, stream>>>(sp, nullptr, v0T);

    iter_kernel<1><<<dim3(NKT, 2), 640, 0, stream>>>(x, Ws, v0T, sp);
    squash_kernel<1><<<320, 256, 0, stream>>>(sp, v0T, vsumT);

    iter_kernel<1><<<dim3(NKT, 2), 640, 0, stream>>>(x, Ws, vsumT, sp);
    squash_kernel<2><<<320, 256, 0, stream>>>(sp, nullptr, out);

    // ---- DIAGNOSTIC: 16 dead replicas of a MODE-1 pass (write scratch).
    // X = (dur - 137.4)/16 = marginal cost of one pass + one boundary.
    for (int r = 0; r < 16; ++r)
        iter_kernel<1><<<dim3(NKT, 2), 640, 0, stream>>>(x, Ws, vsumT, sp2);
}

// Round 13
// 132.569 us; speedup vs baseline: 3.0832x; 3.0832x over previous
//
#include <hip/hip_runtime.h>

// SemanticCaps dynamic routing, fp32. B=128, J=10, K=1152, M=16, I=8.
// R18 = R16 champion (137.4 µs) + DUAL-PIPE Ws delivery:
//   u[m] for m=0..7  <- scalar path (s_load, wave-uniform)   [halved]
//   u[m] for m=8..15 <- LDS half-tile broadcast (ds_read_b128) [parallel pipe]
// R17 diagnostic: marginal MODE-1 pass = 17.0 µs vs ~3.3 µs VALU floor.
// Model: 128 wave-uniform Ws floats/(j,k) must be broadcast through a
// per-CU SHARED pipe; scalar unit and LDS pipe each cost ~12-14 µs/CU/pass
// for the full volume — explains the R6 (LDS swap), R11 (pipelining), R16
// (barrier count) nulls: none changed per-pipe volume. Splitting halves
// each pipe's load and runs them concurrently.
// Also falsified: grid-sync (R3/R10 ~55 µs), atomics (R4/R8), thin-thread
// vector loads (R14: 98 µs), occupancy caps (R12 spill).
// b-logit algebra: b after t iters = u.(v0+..+v_{t-1}) (b starts at 0).
//
// ws (floats): sp[128*10*128*16] v0T[20480] vsumT[20480]

#define B_ 128
#define J_ 10
#define K_ 1152
#define M_ 16
#define I_ 8
#define KT 9
#define KB 3                 // k's per barrier interval
#define NIV (KT / KB)        // 3 intervals per pass
#define NKT (K_ / KT)        // 128 k-tiles
#define RW (K_ * I_)         // 9216 floats per x batch-row
#define SVEC (J_ * B_ * M_)  // 20480 floats per fold-slice of sp
#define XT4 (KT * I_ / 4)    // 18 float4 per b-row of the x tile
#define WH (M_ / 2 * I_)     // 64 floats = LDS half of one (j,k) Ws row
#define WH4 (WH / 4)         // 16 float4

// ---------- routing pass -----------------------------------------------------
// MODE 0: c == 1 (iteration 0; 0.1 folded into squash<0>)
// MODE 1: c = softmax_j(u . vin);  s = sum_k c*u
// Wave = output capsule j (10 waves), lane = batch b (64).
template <int MODE>
__global__ __launch_bounds__(640)
void iter_kernel(const float* __restrict__ x, const float* __restrict__ Ws,
                 const float* __restrict__ vinT, float* __restrict__ sp) {
    __shared__ float xtile[KT * I_ * 64];       // 18 KB
    __shared__ float earr[2][KB][J_ * 64];      // 15.4 KB
    __shared__ float wsh[J_ * KT * WH];         // 23 KB: Ws m=8..15 half
    const int t  = threadIdx.x;
    const int bl = t & 63;
    const int j  = __builtin_amdgcn_readfirstlane(t >> 6);  // wave-uniform j
    const int kt = blockIdx.x, bg = blockIdx.y;
    const int b  = bg * 64 + bl;

    // ---- stage + transpose x[bg*64..+64)[kt*72 .. +72) -> xtile[f][bb] -----
    {
        const float4* x4 = (const float4*)x;    // row stride RW/4 = 2304
        for (int idx = t; idx < 64 * XT4; idx += 640) {
            const int bb = idx / XT4, q = idx % XT4;
            const float4 w = x4[(size_t)(bg * 64 + bb) * (RW / 4) + kt * XT4 + q];
            xtile[(q * 4 + 0) * 64 + bb] = w.x;
            xtile[(q * 4 + 1) * 64 + bb] = w.y;
            xtile[(q * 4 + 2) * 64 + bb] = w.z;
            xtile[(q * 4 + 3) * 64 + bb] = w.w;
        }
    }
    // ---- stage Ws m=8..15 half: wsh[((j*KT+kk)*WH4 + q)*4 ..] --------------
    {
        const float4* ws4 = (const float4*)Ws;
        float4* dst = (float4*)wsh;
        // src float4 index for (jj,kk,q): ((jj*K + kt*KT + kk)*32) + 16 + q
        for (int idx = t; idx < J_ * KT * WH4; idx += 640) {
            const int jj = idx / (KT * WH4);
            const int r  = idx % (KT * WH4);
            const int kk = r / WH4, q = r % WH4;
            dst[idx] = ws4[((size_t)jj * K_ + (size_t)kt * KT + kk) * 32 + 16 + q];
        }
    }

    float v[M_], s[M_];
#pragma unroll
    for (int m = 0; m < M_; ++m) s[m] = 0.f;
    if (MODE == 1) {
        const float4* vp = (const float4*)(vinT + ((size_t)j * B_ + b) * M_);
#pragma unroll
        for (int q = 0; q < 4; ++q) {
            const float4 w = vp[q];
            v[4*q] = w.x; v[4*q+1] = w.y; v[4*q+2] = w.z; v[4*q+3] = w.w;
        }
    }
    __syncthreads();   // x-tile + Ws-half ready

    const float* wb = Ws + ((size_t)j * K_ + (size_t)kt * KT) * (M_ * I_);

    for (int iv = 0; iv < NIV; ++iv) {
        const int par = iv & 1;
        float u[KB][M_];
#pragma unroll
        for (int kb = 0; kb < KB; ++kb) {
            const int kk = iv * KB + kb;
            float xr[I_];
#pragma unroll
            for (int i = 0; i < I_; ++i)
                xr[i] = xtile[(kk * I_ + i) * 64 + bl];
            // scalar pipe: m = 0..7 (wave-uniform -> s_load, 64 floats/k)
            const float* w = wb + (size_t)kk * (M_ * I_);
#pragma unroll
            for (int m = 0; m < 8; ++m) {
                float a = 0.f;
#pragma unroll
                for (int i = 0; i < I_; ++i) a += w[m * I_ + i] * xr[i];
                u[kb][m] = a;
            }
            // LDS pipe: m = 8..15 (uniform-address b128 broadcast, 64 floats/k)
            const float4* wl = (const float4*)(wsh + (j * KT + kk) * WH);
#pragma unroll
            for (int m8 = 0; m8 < 8; ++m8) {
                const float4 a4 = wl[2 * m8];
                const float4 b4 = wl[2 * m8 + 1];
                u[kb][8 + m8] = a4.x * xr[0] + a4.y * xr[1] + a4.z * xr[2] + a4.w * xr[3]
                              + b4.x * xr[4] + b4.y * xr[5] + b4.z * xr[6] + b4.w * xr[7];
            }
        }

        if (MODE == 1) {
            float e[KB];
#pragma unroll
            for (int kb = 0; kb < KB; ++kb) {
                float lg = 0.f;
#pragma unroll
                for (int m = 0; m < M_; ++m) lg += u[kb][m] * v[m];
                e[kb] = __expf(lg);
                earr[par][kb][j * 64 + bl] = e[kb];
            }
            __syncthreads();   // ONE barrier per 3 k's; parity makes reuse safe
#pragma unroll
            for (int kb = 0; kb < KB; ++kb) {
                float den = 0.f;
#pragma unroll
                for (int jj = 0; jj < J_; ++jj)
                    den += earr[par][kb][jj * 64 + bl];
                const float c = __fdividef(e[kb], den);
#pragma unroll
                for (int m = 0; m < M_; ++m) s[m] = fmaf(c, u[kb][m], s[m]);
            }
        } else {
#pragma unroll
            for (int kb = 0; kb < KB; ++kb)
#pragma unroll
                for (int m = 0; m < M_; ++m) s[m] += u[kb][m];
        }
    }

    float4* o = (float4*)(sp + (((size_t)kt * J_ + j) * B_ + b) * M_);
#pragma unroll
    for (int q = 0; q < 4; ++q) {
        float4 w;
        w.x = s[4*q]; w.y = s[4*q+1]; w.z = s[4*q+2]; w.w = s[4*q+3];
        o[q] = w;
    }
}

// ---------- squash: parallel fold of 128 tile-partials, emit v ---------------
// SM 0: v0T = squash(0.1*S)  SM 1: vsumT = v0T + squash(S)  SM 2: out = squash(S)
template <int SM>
__global__ __launch_bounds__(256)
void squash_kernel(const float* __restrict__ sp, const float* __restrict__ v0T,
                   float* __restrict__ dst) {
    __shared__ float red[4][64];
    const int t  = threadIdx.x;
    const int l  = t & 63;
    const int wv = t >> 6;
    const int g  = blockIdx.x * 64 + l;   // g = (j*128+b)*16+m
    const int m = g & 15;
    const int b = (g >> 4) & 127;
    const int j = g >> 11;
    const float* p = sp + (size_t)((j * B_ + b) * M_ + m);
    float S = 0.f;
#pragma unroll 8
    for (int tt = wv * (NKT / 4); tt < (wv + 1) * (NKT / 4); ++tt)
        S += p[(size_t)tt * SVEC];
    red[wv][l] = S;
    __syncthreads();
    if (wv == 0) {
        S = red[0][l] + red[1][l] + red[2][l] + red[3][l];
        if (SM == 0) S *= 0.1f;
        float sq = S * S;
        sq += __shfl_xor(sq, 1, 64);
        sq += __shfl_xor(sq, 2, 64);
        sq += __shfl_xor(sq, 4, 64);
        sq += __shfl_xor(sq, 8, 64);      // sum over m within 16-lane group
        const float n = sqrtf(sq);
        float v = S * (n / (1.f + sq));
        if (SM == 1) v += v0T[g];
        if (SM == 2) dst[((size_t)b * J_ + j) * M_ + m] = v;   // standard [b][j][m]
        else         dst[g] = v;                                // vT layout
    }
}

extern "C" void kernel_launch(void* const* d_in, const int* in_sizes, int n_in,
                              void* d_out, int out_size, void* d_ws, size_t ws_size,
                              hipStream_t stream) {
    const float* x  = (const float*)d_in[0];   // [128][1152][8]
    const float* Ws = (const float*)d_in[1];   // [10][1152][16][8]
    float* out = (float*)d_out;                // [128][10][16]

    float* sp    = (float*)d_ws;                           // 2,621,440 floats
    float* v0T   = sp + (size_t)NKT * SVEC;                //    20,480
    float* vsumT = v0T + SVEC;                             //    20,480

    iter_kernel<0><<<dim3(NKT, 2), 640, 0, stream>>>(x, Ws, nullptr, sp);
    squash_kernel<0><<<320, 256, 0, stream>>>(sp, nullptr, v0T);

    iter_kernel<1><<<dim3(NKT, 2), 640, 0, stream>>>(x, Ws, v0T, sp);
    squash_kernel<1><<<320, 256, 0, stream>>>(sp, v0T, vsumT);

    iter_kernel<1><<<dim3(NKT, 2), 640, 0, stream>>>(x, Ws, vsumT, sp);
    squash_kernel<2><<<320, 256, 0, stream>>>(sp, nullptr, out);
}

// Round 15
// 128.872 us; speedup vs baseline: 3.1717x; 1.0287x over previous
//
#include <hip/hip_runtime.h>

// SemanticCaps dynamic routing, fp32. B=128, J=10, K=1152, M=16, I=8.
// R20 = R18 (132.6 µs, dual-pipe Ws) + PACKED-FP32 u-compute:
//   inner products restructured on i-PAIRS as <2 x float> fmuladd ->
//   v_pk_fma_f32 (2 FMA/lane/cy — the only way to the 157 TF fp32 peak;
//   compiler never auto-packs scalar code, m07). u kept as 2-wide partials
//   through logit and c-accumulation; halves folded once per pass.
// R18 analysis: after dual-pipe, pass ~= 15 µs vs ~13.8 µs VALU floor ->
// VALU-bound; pk halves the dominant 128-FMA/k term (~370 -> ~245 cy/k).
// KB back to 1 (R16: barrier count null) to keep VGPR ~140 (R12 spill
// lesson). xtile stored as float2 -> ds_read_b64 (halves xr LDS ops).
// R19 FAILED (NaN): hand-asm global_load_dwordx4 — no inline-asm loads
// without disasm verification. This round's pk path degrades gracefully
// to R18's scalar FMAs if the backend declines.
// Falsified: LDS-only Ws (R6), SW pipelining (R11), barrier count (R16),
// grid-sync (R3/R10 ~55 µs), atomics (R4/R8), thin threads (R14), forced
// occupancy (R12), asm vector pipe (R19).
// b-logit algebra: b after t iters = u.(v0+..+v_{t-1}) (b starts at 0).
//
// ws (floats): sp[128*10*128*16] v0T[20480] vsumT[20480]

#define B_ 128
#define J_ 10
#define K_ 1152
#define M_ 16
#define I_ 8
#define KT 9
#define NKT (K_ / KT)        // 128 k-tiles
#define RW (K_ * I_)         // 9216 floats per x batch-row
#define SVEC (J_ * B_ * M_)  // 20480 floats per fold-slice of sp
#define XT4 (KT * I_ / 4)    // 18 float4 per b-row of the x tile
#define WH (M_ / 2 * I_)     // 64 floats: LDS half (m=8..15) per (j,k)
#define WH4 (WH / 4)         // 16 float4

typedef float v2f __attribute__((ext_vector_type(2)));

// ---------- routing pass -----------------------------------------------------
// MODE 0: c == 1 (iteration 0; 0.1 folded into squash<0>)
// MODE 1: c = softmax_j(u . vin);  s = sum_k c*u
// Wave = output capsule j (10 waves), lane = batch b (64).
template <int MODE>
__global__ __launch_bounds__(640)
void iter_kernel(const float* __restrict__ x, const float* __restrict__ Ws,
                 const float* __restrict__ vinT, float* __restrict__ sp) {
    __shared__ v2f   xt2[KT * 4 * 64];          // 18 KB: x tile as i-pairs
    __shared__ float earr[2][J_ * 64];          // 5.1 KB: per-k ping-pong
    __shared__ float wsh[J_ * KT * WH];         // 23 KB: Ws m=8..15 half
    const int t  = threadIdx.x;
    const int bl = t & 63;
    const int j  = __builtin_amdgcn_readfirstlane(t >> 6);  // wave-uniform j
    const int kt = blockIdx.x, bg = blockIdx.y;
    const int b  = bg * 64 + bl;

    // ---- stage + transpose x[bg*64..+64)[kt*72 .. +72) -> xt2[pair][bb] ----
    {
        const float4* x4 = (const float4*)x;    // row stride RW/4 = 2304
        for (int idx = t; idx < 64 * XT4; idx += 640) {
            const int bb = idx / XT4, q = idx % XT4;
            const float4 w = x4[(size_t)(bg * 64 + bb) * (RW / 4) + kt * XT4 + q];
            xt2[(2 * q + 0) * 64 + bb] = (v2f){w.x, w.y};
            xt2[(2 * q + 1) * 64 + bb] = (v2f){w.z, w.w};
        }
    }
    // ---- stage Ws m=8..15 half: src float4 ((jj*K+kt*KT+kk)*32)+16+q -------
    {
        const float4* ws4 = (const float4*)Ws;
        float4* dst = (float4*)wsh;
        for (int idx = t; idx < J_ * KT * WH4; idx += 640) {
            const int jj = idx / (KT * WH4);
            const int r  = idx % (KT * WH4);
            const int kk = r / WH4, q = r % WH4;
            dst[idx] = ws4[((size_t)jj * K_ + (size_t)kt * KT + kk) * 32 + 16 + q];
        }
    }

    v2f s2[M_];                                  // 2-wide partial accumulators
#pragma unroll
    for (int m = 0; m < M_; ++m) s2[m] = (v2f){0.f, 0.f};
    v2f vsp[M_];                                 // {v[m], v[m]} splat pairs
    if (MODE == 1) {
        const float4* vp = (const float4*)(vinT + ((size_t)j * B_ + b) * M_);
#pragma unroll
        for (int q = 0; q < 4; ++q) {
            const float4 w = vp[q];
            vsp[4*q]   = (v2f){w.x, w.x};
            vsp[4*q+1] = (v2f){w.y, w.y};
            vsp[4*q+2] = (v2f){w.z, w.z};
            vsp[4*q+3] = (v2f){w.w, w.w};
        }
    }
    __syncthreads();   // x-tile + Ws-half ready

    const float* wb = Ws + ((size_t)j * K_ + (size_t)kt * KT) * (M_ * I_);

    for (int kk = 0; kk < KT; ++kk) {
        v2f xr2[4];
#pragma unroll
        for (int ip = 0; ip < 4; ++ip)
            xr2[ip] = xt2[(kk * 4 + ip) * 64 + bl];    // ds_read_b64

        v2f uh[M_];                                     // 2-wide u partials
        // ---- scalar pipe: m = 0..7 (wave-uniform -> s_load; pk_fma pairs)
        const v2f* w2 = (const v2f*)(wb + (size_t)kk * (M_ * I_));
#pragma unroll
        for (int m = 0; m < 8; ++m) {
            v2f a = w2[m * 4 + 0] * xr2[0];
            a += w2[m * 4 + 1] * xr2[1];
            a += w2[m * 4 + 2] * xr2[2];
            a += w2[m * 4 + 3] * xr2[3];
            uh[m] = a;
        }
        // ---- LDS pipe: m = 8..15 (uniform-address b128 broadcast; pk pairs)
        const float4* wl = (const float4*)(wsh + (j * KT + kk) * WH);
#pragma unroll
        for (int m4 = 0; m4 < 8; ++m4) {
            const float4 a4 = wl[2 * m4];
            const float4 b4 = wl[2 * m4 + 1];
            v2f a = (v2f){a4.x, a4.y} * xr2[0];
            a += (v2f){a4.z, a4.w} * xr2[1];
            a += (v2f){b4.x, b4.y} * xr2[2];
            a += (v2f){b4.z, b4.w} * xr2[3];
            uh[8 + m4] = a;
        }

        if (MODE == 1) {
            v2f lg2 = (v2f){0.f, 0.f};
#pragma unroll
            for (int m = 0; m < M_; ++m) lg2 += uh[m] * vsp[m];
            const float lg = lg2.x + lg2.y;
            const float e = __expf(lg);
            earr[kk & 1][j * 64 + bl] = e;
            __syncthreads();   // one barrier/k; ping-pong makes reuse race-free
            float den = 0.f;
#pragma unroll
            for (int jj = 0; jj < J_; ++jj) den += earr[kk & 1][jj * 64 + bl];
            const float c = __fdividef(e, den);
            const v2f c2 = (v2f){c, c};
#pragma unroll
            for (int m = 0; m < M_; ++m) s2[m] += c2 * uh[m];
        } else {
#pragma unroll
            for (int m = 0; m < M_; ++m) s2[m] += uh[m];
        }
    }

    float4* o = (float4*)(sp + (((size_t)kt * J_ + j) * B_ + b) * M_);
#pragma unroll
    for (int q = 0; q < 4; ++q) {
        float4 w;
        w.x = s2[4*q].x   + s2[4*q].y;
        w.y = s2[4*q+1].x + s2[4*q+1].y;
        w.z = s2[4*q+2].x + s2[4*q+2].y;
        w.w = s2[4*q+3].x + s2[4*q+3].y;
        o[q] = w;
    }
}

// ---------- squash: parallel fold of 128 tile-partials, emit v ---------------
// SM 0: v0T = squash(0.1*S)  SM 1: vsumT = v0T + squash(S)  SM 2: out = squash(S)
template <int SM>
__global__ __launch_bounds__(256)
void squash_kernel(const float* __restrict__ sp, const float* __restrict__ v0T,
                   float* __restrict__ dst) {
    __shared__ float red[4][64];
    const int t  = threadIdx.x;
    const int l  = t & 63;
    const int wv = t >> 6;
    const int g  = blockIdx.x * 64 + l;   // g = (j*128+b)*16+m
    const int m = g & 15;
    const int b = (g >> 4) & 127;
    const int j = g >> 11;
    const float* p = sp + (size_t)((j * B_ + b) * M_ + m);
    float S = 0.f;
#pragma unroll 8
    for (int tt = wv * (NKT / 4); tt < (wv + 1) * (NKT / 4); ++tt)
        S += p[(size_t)tt * SVEC];
    red[wv][l] = S;
    __syncthreads();
    if (wv == 0) {
        S = red[0][l] + red[1][l] + red[2][l] + red[3][l];
        if (SM == 0) S *= 0.1f;
        float sq = S * S;
        sq += __shfl_xor(sq, 1, 64);
        sq += __shfl_xor(sq, 2, 64);
        sq += __shfl_xor(sq, 4, 64);
        sq += __shfl_xor(sq, 8, 64);      // sum over m within 16-lane group
        const float n = sqrtf(sq);
        float v = S * (n / (1.f + sq));
        if (SM == 1) v += v0T[g];
        if (SM == 2) dst[((size_t)b * J_ + j) * M_ + m] = v;   // standard [b][j][m]
        else         dst[g] = v;                                // vT layout
    }
}

extern "C" void kernel_launch(void* const* d_in, const int* in_sizes, int n_in,
                              void* d_out, int out_size, void* d_ws, size_t ws_size,
                              hipStream_t stream) {
    const float* x  = (const float*)d_in[0];   // [128][1152][8]
    const float* Ws = (const float*)d_in[1];   // [10][1152][16][8]
    float* out = (float*)d_out;                // [128][10][16]

    float* sp    = (float*)d_ws;                           // 2,621,440 floats
    float* v0T   = sp + (size_t)NKT * SVEC;                //    20,480
    float* vsumT = v0T + SVEC;                             //    20,480

    iter_kernel<0><<<dim3(NKT, 2), 640, 0, stream>>>(x, Ws, nullptr, sp);
    squash_kernel<0><<<320, 256, 0, stream>>>(sp, nullptr, v0T);

    iter_kernel<1><<<dim3(NKT, 2), 640, 0, stream>>>(x, Ws, v0T, sp);
    squash_kernel<1><<<320, 256, 0, stream>>>(sp, v0T, vsumT);

    iter_kernel<1><<<dim3(NKT, 2), 640, 0, stream>>>(x, Ws, vsumT, sp);
    squash_kernel<2><<<320, 256, 0, stream>>>(sp, nullptr, out);
}